// Round 7
// baseline (686.426 us; speedup 1.0000x reference)
//
#include <hip/hip_runtime.h>

#define DEV __device__ __forceinline__

typedef float f32x4 __attribute__((ext_vector_type(4)));
typedef short s16x8 __attribute__((ext_vector_type(8)));
typedef short s16x4 __attribute__((ext_vector_type(4)));

// ---------- scalar helpers ----------
DEV unsigned short f2bf(float f){
  unsigned int u = __float_as_uint(f);
  u += 0x7fffu + ((u>>16)&1u);
  return (unsigned short)(u>>16);
}
DEV float bf2f(unsigned short h){ return __uint_as_float(((unsigned int)h)<<16); }

#if __has_builtin(__builtin_amdgcn_rcpf)
DEV float frcp_(float x){ return __builtin_amdgcn_rcpf(x); }
#else
DEV float frcp_(float x){ return 1.f/x; }
#endif
#if __has_builtin(__builtin_amdgcn_exp2f)
DEV float fexp2_(float x){ return __builtin_amdgcn_exp2f(x); }
#else
DEV float fexp2_(float x){ return exp2f(x); }
#endif

DEV float tanh_(float x){
  x = fminf(x, 30.f);
  float e = fexp2_(2.8853900817779268f*x);
  return (e-1.f)*frcp_(e+1.f);
}

// branchless f32 -> OCP e4m3fn (fallback when no HW cvt)
DEV unsigned char f2e4m3(float x){
  unsigned int u = __float_as_uint(x);
  unsigned int s = (u>>24)&0x80u;
  unsigned int mag = u & 0x7fffffffu;
  if (mag > 0x43E00000u) mag = 0x43E00000u;
  mag += 0x000FFFFFu + ((mag>>20)&1u);
  int e = (int)(mag>>23) - 120;
  unsigned int m = (mag>>20)&7u;
  unsigned int r = (e<=0) ? 0u : (((unsigned)e<<3)|m);
  return (unsigned char)(s|r);
}

DEV f32x4 mfma_bf16(s16x8 a, s16x8 b, f32x4 c){
  return __builtin_amdgcn_mfma_f32_16x16x32_bf16(a,b,c,0,0,0);
}
DEV f32x4 mfma_fp8(long a, long b, f32x4 c){
  return __builtin_amdgcn_mfma_f32_16x16x32_fp8_fp8(a,b,c,0,0,0);
}

// LDS-only barrier (no vmcnt drain)
DEV void lds_barrier(){
  asm volatile("s_waitcnt lgkmcnt(0)\n\ts_barrier" ::: "memory");
}

// ---------- agent-scope flag ops (cross-XCD per G16) ----------
DEV unsigned aload_acq(unsigned* p){
  return __hip_atomic_load(p, __ATOMIC_ACQUIRE, __HIP_MEMORY_SCOPE_AGENT);
}
DEV void astore_rel(unsigned* p, unsigned v){
  __hip_atomic_store(p, v, __ATOMIC_RELEASE, __HIP_MEMORY_SCOPE_AGENT);
}
DEV void aadd_rel(unsigned* p, unsigned v){
  __hip_atomic_fetch_add(p, v, __ATOMIC_RELEASE, __HIP_MEMORY_SCOPE_AGENT);
}
DEV void spin_ge(unsigned* p, unsigned tgt){
  while (aload_acq(p) < tgt) __builtin_amdgcn_s_sleep(2);
}

// ---------- problem constants ----------
#define Bx 128
#define Vx 64
#define Sx 40
#define Dx 256
#define Hx 256

// d_out element offsets (f32)
#define OFF_OG   0
#define OFF_FAKE 256
#define OFF_DECV 512
#define OFF_GENV 2097664
#define OFF_STS  4194816
#define OFF_LBL  4203008

// bf16 weight-pool element offsets
#define PW_IH  0
#define PW_HH  262144
#define PW_HK  524288
#define PW_1   589824
#define PC_1   622592
#define PC_2   884736
#define PC_O   1409024
#define P_TOT  1410048

#define HPB 264      // scan LDS row pitch (bytes)
#define WHP 272      // worker wh LDS pitch (shorts); 136 dw % 32 = 8 -> 4-way max

// ---------- PRE: embed + weight cvt + flags/passthrough ----------
__global__ void k_pre(const int* __restrict__ seqs, const float* __restrict__ emb,
                      unsigned short* __restrict__ v16,
                      float* __restrict__ decv, float* __restrict__ genv,
                      unsigned short* __restrict__ barv16,
                      const float* __restrict__ W_ih, const float* __restrict__ Whh,
                      const float* __restrict__ Whk, const float* __restrict__ W1,
                      const float* __restrict__ C1W, const float* __restrict__ C2W,
                      const float* __restrict__ CoW,
                      unsigned short* __restrict__ pool, unsigned char* __restrict__ whh8,
                      const float* __restrict__ sts, const int* __restrict__ label,
                      float* __restrict__ out, unsigned* __restrict__ flags){
  int bx = blockIdx.x, tid = threadIdx.x;
  if (bx < 8192){                       // embed: v = sum_s relu(emb[idx])
    int bt = bx, d = tid;
    const int* sp = seqs + (size_t)bt*Sx;
    float acc = 0.f;
    #pragma unroll 4
    for (int s=0;s<Sx;s++) acc += fmaxf(emb[(size_t)sp[s]*Dx + d], 0.f);
    size_t o = (size_t)bt*Dx + d;
    v16[o] = f2bf(acc);
    if ((bt & 63) == 0){ decv[o] = acc; genv[o] = acc; barv16[o] = f2bf(acc); }
    return;
  }
  if (bx < 14724){                      // weight conversions
    int i = (bx-8192)*256 + tid;
    if (i < P_TOT){
      float v;
      if      (i < PW_HH) v = W_ih[i - PW_IH];
      else if (i < PW_HK) v = Whh [i - PW_HH];
      else if (i < PW_1 ) v = Whk [i - PW_HK];
      else if (i < PC_1 ) v = W1  [i - PW_1 ];
      else if (i < PC_2 ) v = C1W [i - PC_1 ];
      else if (i < PC_O ) v = C2W [i - PC_2 ];
      else                v = CoW [i - PC_O ];
      pool[i] = f2bf(v);
    } else if (i < P_TOT + 262144){
      whh8[i - P_TOT] = f2e4m3(16.f*Whh[i - P_TOT]);
    }
    return;
  }
  // misc block: flags init + passthrough outputs
  if (tid < 200) flags[tid] = (tid==64) ? 1u : 0u;   // bvf[0] = 1
  for (int i=tid;i<Bx*Vx;i+=256) out[OFF_STS + i] = sts[i];
  if (tid < Bx) out[OFF_LBL + tid] = (float)label[tid];
}

// ---------- generic MFMA GEMM (xg1 + classifier layers) ----------
// MODE_A: 0 = row-major rows m (pitch K); 1 = v-layout [b][t][d], m = t*128+b
// MODE_C: 0 = row-major [m][n] bf16 (pitch Ntot); 1 = xg layout [t][g][n][16b]
template<int MODE_A, int MODE_C, int RELU>
__global__ void k_gemm(const unsigned short* __restrict__ A, const unsigned short* __restrict__ Bw,
                       const float* __restrict__ bias1, const float* __restrict__ bias2,
                       unsigned short* __restrict__ C, int K, int Ntot, float scale){
  int tid = threadIdx.x, w = tid>>6, l = tid&63, lm = l&15, q = l>>4;
  int m0 = blockIdx.x*64;
  int n0 = blockIdx.y*256 + w*64;
  f32x4 acc[4][4];
  #pragma unroll
  for (int nt=0;nt<4;nt++){
    int n = n0 + nt*16 + lm;
    float bz = bias1 ? bias1[n] : 0.f;
    if (bias2) bz += bias2[n];
    #pragma unroll
    for (int mt=0;mt<4;mt++) acc[mt][nt] = (f32x4){bz,bz,bz,bz};
  }
  const s16x8* Arow[4];
  #pragma unroll
  for (int mt=0;mt<4;mt++){
    int m = m0 + mt*16 + lm;
    size_t off = (MODE_A==0) ? (size_t)m*K : ((size_t)(m&127)*Vx + (m>>7))*(size_t)K;
    Arow[mt] = (const s16x8*)(A + off);
  }
  int kkn = K/32;
  for (int kk=0; kk<kkn; kk++){
    s16x8 bfr[4];
    #pragma unroll
    for (int nt=0;nt<4;nt++){
      int n = n0 + nt*16 + lm;
      bfr[nt] = *(const s16x8*)(Bw + (size_t)n*K + kk*32 + q*8);
    }
    #pragma unroll
    for (int mt=0;mt<4;mt++){
      s16x8 afr = Arow[mt][kk*4 + q];
      #pragma unroll
      for (int nt=0;nt<4;nt++)
        acc[mt][nt] = mfma_bf16(afr, bfr[nt], acc[mt][nt]);
    }
  }
  #pragma unroll
  for (int mt=0;mt<4;mt++){
    int mbase = m0 + mt*16 + q*4;
    #pragma unroll
    for (int nt=0;nt<4;nt++){
      int n = n0 + nt*16 + lm;
      if (MODE_C==0){
        #pragma unroll
        for (int r=0;r<4;r++){
          float val = scale*acc[mt][nt][r];
          if (RELU) val = fmaxf(val, 0.f);
          C[(size_t)(mbase+r)*Ntot + n] = f2bf(val);
        }
      } else {
        int tt = mbase>>7, bb = mbase&127;
        int gg = bb>>4;
        s16x4 sv;
        #pragma unroll
        for (int r=0;r<4;r++) sv[r] = (short)f2bf(scale*acc[mt][nt][r]);
        *(s16x4*)(C + (((size_t)tt*8 + gg)*1024 + n)*16 + (bb&15)) = sv;
      }
    }
  }
}

// ---------- scan body (shared by scan1/scan2) ----------
template<int IS1>
DEV void scan_body(unsigned char* hl, const unsigned char* __restrict__ W8,
                   const unsigned short* __restrict__ xg, unsigned short* __restrict__ hist,
                   int g, unsigned* __restrict__ ctr1, unsigned* __restrict__ xgf){
  int tid = threadIdx.x;
  int w = tid>>6, l = tid&63, lm = l&15, q = l>>4;
  int j = w*16 + lm;
  for (int i=tid;i<2*16*HPB;i+=1024) hl[i] = 0;
  long Bf[4][8];
  #pragma unroll
  for (int qq=0;qq<4;qq++){
    int n = qq*256 + j;
    #pragma unroll
    for (int kk=0;kk<8;kk++)
      Bf[qq][kk] = *(const long*)(W8 + (size_t)n*256 + kk*32 + q*8);
  }
  float cst[4] = {0.f,0.f,0.f,0.f};
  const unsigned short* xgb = xg + (size_t)g*16384 + q*4;
  s16x4 xc[4], xn[4];
  if (!IS1) spin_ge(&xgf[0], 1);
  #pragma unroll
  for (int qq=0;qq<4;qq++) xc[qq] = *(const s16x4*)(xgb + (qq*256+j)*16);
  __syncthreads();
  const float K1 = 1.4426950408889634f/256.f;
  const unsigned char* hrd = hl + lm*HPB + q*8;
  #pragma unroll 1
  for (int t=0;t<Vx;t++){
    if (t < Vx-1){
      if (!IS1) spin_ge(&xgf[t+1], 1);
      #pragma unroll
      for (int qq=0;qq<4;qq++)
        xn[qq] = *(const s16x4*)(xgb + (size_t)(t+1)*131072 + (qq*256+j)*16);
    }
    const unsigned char* hb = hrd + (t&1)*(16*HPB);
    f32x4 a0, a1, a2, a3;
    #pragma unroll
    for (int r=0;r<4;r++){
      a0[r] = bf2f((unsigned short)xc[0][r]);
      a1[r] = bf2f((unsigned short)xc[1][r]);
      a2[r] = bf2f((unsigned short)xc[2][r]);
      a3[r] = bf2f((unsigned short)xc[3][r]);
    }
    #pragma unroll
    for (int kk=0;kk<8;kk++){
      long af = *(const long*)(hb + kk*32);
      a0 = mfma_fp8(af, Bf[0][kk], a0);
      a1 = mfma_fp8(af, Bf[1][kk], a1);
      a2 = mfma_fp8(af, Bf[2][kk], a2);
      a3 = mfma_fp8(af, Bf[3][kk], a3);
    }
    unsigned char* hn = hl + ((t+1)&1)*(16*HPB) + j;
    float hv16[4];
    #pragma unroll
    for (int r=0;r<4;r++){
      float iv = frcp_(1.f + fexp2_(-K1*a0[r]));
      float fv = frcp_(1.f + fexp2_(-K1*a1[r]));
      float eg = fexp2_(2.f*K1*a2[r]);
      float gv = (eg-1.f)*frcp_(eg+1.f);
      float ov = frcp_(1.f + fexp2_(-K1*a3[r]));
      float cv = fv*cst[r] + iv*gv;
      cst[r] = cv;
      float ec = fexp2_(2.8853900817779268f*fminf(cv,30.f));
      float hv = ov*(ec-1.f)*frcp_(ec+1.f);
      hv16[r] = 16.f*hv;
      if (IS1)
        hist[((size_t)t*Bx + g*16 + q*4 + r)*Hx + j] = f2bf(hv);
      else if (t==Vx-1)
        hist[((size_t)(g*16 + q*4 + r))*Hx + j] = f2bf(hv);
    }
#if __has_builtin(__builtin_amdgcn_cvt_pk_fp8_f32)
    int p01 = __builtin_amdgcn_cvt_pk_fp8_f32(hv16[0], hv16[1], 0, false);
    int p23 = __builtin_amdgcn_cvt_pk_fp8_f32(hv16[2], hv16[3], 0, false);
    hn[(q*4+0)*HPB] = (unsigned char)p01;
    hn[(q*4+1)*HPB] = (unsigned char)(p01>>8);
    hn[(q*4+2)*HPB] = (unsigned char)p23;
    hn[(q*4+3)*HPB] = (unsigned char)(p23>>8);
#else
    #pragma unroll
    for (int r=0;r<4;r++) hn[(q*4+r)*HPB] = f2e4m3(hv16[r]);
#endif
    #pragma unroll
    for (int qq=0;qq<4;qq++) xc[qq] = xn[qq];
    if (IS1){
      __syncthreads();                       // drains vmcnt for all waves
      if (tid == 0) aadd_rel(&ctr1[t], 1);   // publish h[t] (hist1 rows)
    } else {
      lds_barrier();
    }
  }
}

// ---------- per-t chain worker: wh -> attn -> barv -> xg2 ----------
DEV void worker_body(unsigned short* whs, int t,
    const unsigned short* __restrict__ hist1, const unsigned short* __restrict__ v16,
    const float* __restrict__ u, const unsigned short* __restrict__ pool,
    const float* __restrict__ bhk, const float* __restrict__ W2, const float* __restrict__ b2,
    const float* __restrict__ b_ih, const float* __restrict__ b_hh,
    float* __restrict__ decv, float* __restrict__ genv,
    unsigned short* __restrict__ barv16, unsigned short* __restrict__ xg2,
    unsigned* ctr1, unsigned* bvf, unsigned* xgf, unsigned* uctr){
  int tid = threadIdx.x, w = tid>>6, l = tid&63, lm = l&15, q = l>>4;
  if (t < 63){
    spin_ge(&ctr1[t], 8);                       // wait scan1 step t (all 8 blocks)
    // ---- wh tile: 128x256, wave w -> rows (w&7)*16, cols (w>>3)*128 ----
    int r0 = (w&7)*16, n0 = (w>>3)*128;
    const s16x8* Arow = (const s16x8*)(hist1 + ((size_t)t*Bx + r0 + lm)*Hx);
    f32x4 acc[8];
    #pragma unroll
    for (int nt=0;nt<8;nt++){
      float bz = bhk[n0 + nt*16 + lm];
      acc[nt] = (f32x4){bz,bz,bz,bz};
    }
    #pragma unroll
    for (int kk=0;kk<8;kk++){
      s16x8 afr = Arow[kk*4 + q];
      #pragma unroll
      for (int nt=0;nt<8;nt++){
        int n = n0 + nt*16 + lm;
        s16x8 bfr = *(const s16x8*)(pool + PW_HK + (size_t)n*256 + kk*32 + q*8);
        acc[nt] = mfma_bf16(afr, bfr, acc[nt]);
      }
    }
    #pragma unroll
    for (int nt=0;nt<8;nt++){
      int n = n0 + nt*16 + lm, mb = r0 + q*4;
      #pragma unroll
      for (int r=0;r<4;r++) whs[(size_t)(mb+r)*WHP + n] = f2bf(acc[nt][r]);
    }
    spin_ge(uctr, 8);                           // u ready (set once, cheap)
    __syncthreads();
    // ---- attn on waves 0..7 (16 rows each) ----
    if (w < 8){
      int m0l = w*16;
      f32x4 a2[4];
      #pragma unroll
      for (int nt=0;nt<4;nt++){
        int n = nt*16 + lm;
        #pragma unroll
        for (int r=0;r<4;r++) a2[nt][r] = u[(size_t)(m0l + q*4 + r)*64 + n];
      }
      #pragma unroll
      for (int kk=0;kk<8;kk++){
        s16x8 afr = *(const s16x8*)(whs + (size_t)(m0l+lm)*WHP + kk*32 + q*8);
        #pragma unroll
        for (int nt=0;nt<4;nt++){
          int n = nt*16 + lm;
          s16x8 bfr = *(const s16x8*)(pool + PW_1 + (size_t)n*512 + 256 + kk*32 + q*8);
          a2[nt] = mfma_bf16(afr, bfr, a2[nt]);
        }
      }
      float p0a[4] = {0,0,0,0}, p1a[4] = {0,0,0,0};
      #pragma unroll
      for (int nt=0;nt<4;nt++){
        int n = nt*16 + lm;
        float w2a = W2[n], w2b = W2[64+n];
        #pragma unroll
        for (int r=0;r<4;r++){
          float z = tanh_(a2[nt][r]);
          p0a[r] += z*w2a; p1a[r] += z*w2b;
        }
      }
      #pragma unroll
      for (int s=1;s<16;s<<=1){
        #pragma unroll
        for (int r=0;r<4;r++){ p0a[r] += __shfl_xor(p0a[r], s, 16); p1a[r] += __shfl_xor(p1a[r], s, 16); }
      }
      float bb0 = b2[0], bb1 = b2[1];
      int d0 = lm*16;
      #pragma unroll
      for (int r=0;r<4;r++){
        int b = m0l + q*4 + r;
        float g0 = p0a[r]+bb0, g1 = p1a[r]+bb1;
        float al0 = frcp_(1.f + fexp2_(1.4426950408889634f*(g1-g0)));
        float al1 = 1.f - al0;
        const unsigned short* ek  = v16 + (size_t)b*Vx*Dx + d0;      // v[b][0][:]
        const unsigned short* whp = whs + (size_t)b*WHP + d0;
        size_t ob = ((size_t)b*Vx + (t+1))*Dx + d0;
        #pragma unroll
        for (int c=0;c<2;c++){
          s16x8 e8 = *(const s16x8*)(ek + c*8);
          s16x8 w8 = *(const s16x8*)(whp + c*8);
          s16x8 o16;
          #pragma unroll
          for (int jj=0;jj<8;jj++){
            float o = al0*bf2f((unsigned short)e8[jj]) + al1*bf2f((unsigned short)w8[jj]);
            decv[ob + c*8 + jj] = o;
            genv[ob + c*8 + jj] = o;
            o16[jj] = (short)f2bf(o);
          }
          *(s16x8*)(barv16 + ob + c*8) = o16;
        }
      }
    }
    __syncthreads();                            // drains barv stores (all waves)
    if (tid == 0) astore_rel(&bvf[t+1], 1);
  }
  // ---- phase B: xg2 tile t (128 x 1024, K=256) ----
  spin_ge(&bvf[t], 1);
  int mh = (w&1)*64, nb = (w>>1)*128;
  const s16x8* Arow2[4];
  #pragma unroll
  for (int mt=0;mt<4;mt++)
    Arow2[mt] = (const s16x8*)(barv16 + ((size_t)(mh + mt*16 + lm)*Vx + t)*Dx);
  #pragma unroll 1
  for (int sc=0; sc<4; sc++){
    int n0 = nb + sc*32;
    f32x4 acc[4][2];
    #pragma unroll
    for (int nt=0;nt<2;nt++){
      int n = n0 + nt*16 + lm;
      float bz = b_ih[n] + b_hh[n];
      #pragma unroll
      for (int mt=0;mt<4;mt++) acc[mt][nt] = (f32x4){bz,bz,bz,bz};
    }
    #pragma unroll
    for (int kk=0;kk<8;kk++){
      s16x8 bfr[2];
      #pragma unroll
      for (int nt=0;nt<2;nt++){
        int n = n0 + nt*16 + lm;
        bfr[nt] = *(const s16x8*)(pool + PW_IH + (size_t)n*256 + kk*32 + q*8);
      }
      #pragma unroll
      for (int mt=0;mt<4;mt++){
        s16x8 afr = Arow2[mt][kk*4 + q];
        acc[mt][0] = mfma_bf16(afr, bfr[0], acc[mt][0]);
        acc[mt][1] = mfma_bf16(afr, bfr[1], acc[mt][1]);
      }
    }
    #pragma unroll
    for (int mt=0;mt<4;mt++){
      int m = mh + mt*16 + q*4;
      int gg = m>>4;
      #pragma unroll
      for (int nt=0;nt<2;nt++){
        int n = n0 + nt*16 + lm;
        s16x4 sv;
        #pragma unroll
        for (int r=0;r<4;r++) sv[r] = (short)f2bf(256.f*acc[mt][nt][r]);
        *(s16x4*)(xg2 + (((size_t)t*8 + gg)*1024 + n)*16 + (m&15)) = sv;
      }
    }
  }
  __syncthreads();
  if (tid == 0) astore_rel(&xgf[t], 1);
}

// ---------- MEGA: scan1 || workers || scan2 || u ----------
__global__ __launch_bounds__(1024) void k_mega(
    const unsigned char* __restrict__ W8,
    const unsigned short* __restrict__ xg1, unsigned short* __restrict__ xg2,
    unsigned short* __restrict__ hist1, unsigned short* __restrict__ h2,
    const unsigned short* __restrict__ v16, float* __restrict__ u,
    const unsigned short* __restrict__ pool,
    const float* __restrict__ bhk, const float* __restrict__ W2, const float* __restrict__ b2,
    const float* __restrict__ b1, const float* __restrict__ b_ih, const float* __restrict__ b_hh,
    float* __restrict__ decv, float* __restrict__ genv, unsigned short* __restrict__ barv16,
    unsigned* __restrict__ flags){
  __shared__ __align__(16) unsigned char smem[69632];
  unsigned* ctr1 = flags;
  unsigned* bvf  = flags + 64;
  unsigned* xgf  = flags + 128;
  unsigned* uctr = flags + 192;
  int blk = blockIdx.x;
  if (blk < 8){
    scan_body<1>(smem, W8, xg1, hist1, blk, ctr1, xgf);
  } else if (blk < 16){
    scan_body<0>(smem, W8, xg2, h2, blk-8, ctr1, xgf);
  } else if (blk < 80){
    worker_body((unsigned short*)smem, blk-16, hist1, v16, u, pool, bhk, W2, b2,
                b_ih, b_hh, decv, genv, barv16, xg2, ctr1, bvf, xgf, uctr);
  } else {
    // u GEMV: 8 blocks x 1024 threads = 8192 = 128 b x 64 n
    int t2 = (blk-80)*1024 + threadIdx.x;
    int b = t2>>6, n = t2&63;
    const s16x8* vr = (const s16x8*)(v16 + (size_t)b*Vx*Dx);
    const s16x8* wr = (const s16x8*)(pool + PW_1 + (size_t)n*512);
    float a = b1[n];
    for (int kk=0;kk<32;kk++){
      s16x8 x = vr[kk], ww = wr[kk];
      #pragma unroll
      for (int jj=0;jj<8;jj++) a += bf2f((unsigned short)x[jj])*bf2f((unsigned short)ww[jj]);
    }
    u[t2] = a;
    __syncthreads();
    if (threadIdx.x == 0) aadd_rel(uctr, 1);
  }
}

// ---------- final logits: out = y2 @ CoW^T + Cob ----------
__global__ void k_out(const unsigned short* __restrict__ y2, const unsigned short* __restrict__ CoW16,
                      const float* __restrict__ Cob, float* __restrict__ out){
  int tid = blockIdx.x*256 + threadIdx.x;
  int m = tid>>1, n = tid&1;
  const s16x8* yr = (const s16x8*)(y2 + (size_t)m*512);
  const s16x8* wr = (const s16x8*)(CoW16 + (size_t)n*512);
  float a = Cob[n];
  for (int kk=0;kk<64;kk++){
    s16x8 yv = yr[kk], ww = wr[kk];
    #pragma unroll
    for (int jj=0;jj<8;jj++) a += bf2f((unsigned short)yv[jj])*bf2f((unsigned short)ww[jj]);
  }
  int base = (m < 128) ? (OFF_OG + m*2) : (OFF_FAKE + (m-128)*2);
  out[base + n] = a;
}

// ---------- launch ----------
extern "C" void kernel_launch(void* const* d_in, const int* in_sizes, int n_in,
                              void* d_out, int out_size, void* d_ws, size_t ws_size,
                              hipStream_t stream) {
  const int*   seqs  = (const int*)d_in[0];
  const float* sts   = (const float*)d_in[3];
  const int*   label = (const int*)d_in[5];
  const float* emb   = (const float*)d_in[6];
  const float* W_ih  = (const float*)d_in[7];
  const float* W_hh  = (const float*)d_in[8];
  const float* b_ih  = (const float*)d_in[9];
  const float* b_hh  = (const float*)d_in[10];
  const float* Whk   = (const float*)d_in[11];
  const float* bhk   = (const float*)d_in[12];
  const float* W1    = (const float*)d_in[13];
  const float* b1    = (const float*)d_in[14];
  const float* W2    = (const float*)d_in[15];
  const float* b2    = (const float*)d_in[16];
  const float* C1b   = (const float*)d_in[18];
  const float* C2b   = (const float*)d_in[20];
  const float* Cob   = (const float*)d_in[22];
  float* out = (float*)d_out;

  char* ws = (char*)d_ws;
  unsigned short* v16    = (unsigned short*)(ws + 0);            //  4 MiB [b][t][d] bf16
  unsigned short* xg1    = (unsigned short*)(ws + (4<<20));      // 16 MiB [t][g][n][16] (x256)
  unsigned short* hist1  = (unsigned short*)(ws + (20<<20));     //  4 MiB [t][b][j] + 64K h2
  unsigned short* barv16 = (unsigned short*)(ws + (25<<20));     //  4 MiB [b][t][d] bf16
  unsigned short* xg2    = (unsigned short*)(ws + (29<<20));     // 16 MiB (workers write)
  float*          u      = (float*)(ws + (45<<20));              // 32 KiB
  unsigned char*  whh8   = (unsigned char*)(ws + (45<<20) + (64<<10));   // 256 KiB
  unsigned*       flags  = (unsigned*)(ws + (45<<20) + (320<<10));       // 1 KiB
  unsigned short* pool   = (unsigned short*)(ws + (45<<20) + (512<<10)); // 2.82 MiB
  unsigned short* y1     = xg1;                                  // overlay (xg1 dead post-mega)
  unsigned short* y2     = xg1 + 262144;

  unsigned short* h2 = hist1 + (size_t)Vx*Bx*Hx;
  unsigned short* X  = hist1 + (size_t)(Vx-1)*Bx*Hx;   // [256][256]: h1[63] ; h2

  float* decv = out + OFF_DECV;
  float* genv = out + OFF_GENV;

  k_pre<<<dim3(14725), dim3(256), 0, stream>>>(seqs, emb, v16, decv, genv, barv16,
      W_ih, W_hh, Whk, W1, (const float*)d_in[17], (const float*)d_in[19],
      (const float*)d_in[21], pool, whh8, sts, label, out, flags);
  k_gemm<1,1,0><<<dim3(128,4), dim3(256), 0, stream>>>(v16, pool+PW_IH, b_ih, b_hh, xg1, 256, 1024, 256.f);
  k_mega<<<dim3(88), dim3(1024), 0, stream>>>(whh8, xg1, xg2, hist1, h2, v16, u, pool,
      bhk, W2, b2, b1, b_ih, b_hh, decv, genv, barv16, flags);
  k_gemm<0,0,1><<<dim3(4,4), dim3(256), 0, stream>>>(X, pool+PC_1, C1b, nullptr, y1, 256, 1024, 1.f);
  k_gemm<0,0,1><<<dim3(4,2), dim3(256), 0, stream>>>(y1, pool+PC_2, C2b, nullptr, y2, 1024, 512, 1.f);
  k_out<<<dim3(2), dim3(256), 0, stream>>>(y2, pool+PC_O, Cob, out);
}

// Round 8
// 552.483 us; speedup vs baseline: 1.2424x; 1.2424x over previous
//
#include <hip/hip_runtime.h>

#define DEV __device__ __forceinline__

typedef float f32x4 __attribute__((ext_vector_type(4)));
typedef short s16x8 __attribute__((ext_vector_type(8)));
typedef short s16x4 __attribute__((ext_vector_type(4)));

// ---------- scalar helpers ----------
DEV unsigned short f2bf(float f){
  unsigned int u = __float_as_uint(f);
  u += 0x7fffu + ((u>>16)&1u);
  return (unsigned short)(u>>16);
}
DEV float bf2f(unsigned short h){ return __uint_as_float(((unsigned int)h)<<16); }

#if __has_builtin(__builtin_amdgcn_rcpf)
DEV float frcp_(float x){ return __builtin_amdgcn_rcpf(x); }
#else
DEV float frcp_(float x){ return 1.f/x; }
#endif
#if __has_builtin(__builtin_amdgcn_exp2f)
DEV float fexp2_(float x){ return __builtin_amdgcn_exp2f(x); }
#else
DEV float fexp2_(float x){ return exp2f(x); }
#endif

DEV float tanh_(float x){
  x = fminf(x, 30.f);
  float e = fexp2_(2.8853900817779268f*x);
  return (e-1.f)*frcp_(e+1.f);
}

// branchless f32 -> OCP e4m3fn (fallback when no HW cvt)
DEV unsigned char f2e4m3(float x){
  unsigned int u = __float_as_uint(x);
  unsigned int s = (u>>24)&0x80u;
  unsigned int mag = u & 0x7fffffffu;
  if (mag > 0x43E00000u) mag = 0x43E00000u;
  mag += 0x000FFFFFu + ((mag>>20)&1u);
  int e = (int)(mag>>23) - 120;
  unsigned int m = (mag>>20)&7u;
  unsigned int r = (e<=0) ? 0u : (((unsigned)e<<3)|m);
  return (unsigned char)(s|r);
}

DEV f32x4 mfma_bf16(s16x8 a, s16x8 b, f32x4 c){
  return __builtin_amdgcn_mfma_f32_16x16x32_bf16(a,b,c,0,0,0);
}
DEV f32x4 mfma_fp8(long a, long b, f32x4 c){
  return __builtin_amdgcn_mfma_f32_16x16x32_fp8_fp8(a,b,c,0,0,0);
}

// LDS-only barrier (no vmcnt drain)
DEV void lds_barrier(){
  asm volatile("s_waitcnt lgkmcnt(0)\n\ts_barrier" ::: "memory");
}

// ---------- agent-scope flag ops; one flag per 128-B line (stride 32 ints) ----------
DEV unsigned aload_acq(unsigned* p){
  return __hip_atomic_load(p, __ATOMIC_ACQUIRE, __HIP_MEMORY_SCOPE_AGENT);
}
DEV void astore_rel(unsigned* p, unsigned v){
  __hip_atomic_store(p, v, __ATOMIC_RELEASE, __HIP_MEMORY_SCOPE_AGENT);
}
DEV void aadd_rel(unsigned* p, unsigned v){
  __hip_atomic_fetch_add(p, v, __ATOMIC_RELEASE, __HIP_MEMORY_SCOPE_AGENT);
}
DEV void spin_ge(unsigned* p, unsigned tgt){
  while (aload_acq(p) < tgt) __builtin_amdgcn_s_sleep(8);
}
// block-level wait: ONLY tid0 polls; barrier broadcasts the result
DEV void block_wait_ge(unsigned* p, unsigned tgt){
  if (threadIdx.x == 0) spin_ge(p, tgt);
  __syncthreads();
}

// ---------- problem constants ----------
#define Bx 128
#define Vx 64
#define Sx 40
#define Dx 256
#define Hx 256
#define NVOC 20001

// d_out element offsets (f32)
#define OFF_OG   0
#define OFF_FAKE 256
#define OFF_DECV 512
#define OFF_GENV 2097664
#define OFF_STS  4194816
#define OFF_LBL  4203008

// bf16 weight-pool element offsets
#define PW_IH  0
#define PW_HH  262144
#define PW_HK  524288
#define PW_1   589824
#define PC_1   622592
#define PC_2   884736
#define PC_O   1409024
#define P_TOT  1410048

#define HPB 264      // scan LDS row pitch (bytes)
#define WHP 272      // worker wh LDS pitch (shorts)

// flag slots (ints): one per 128-B line
#define FCT(t) ((t)*32)
#define FBV(t) (2048 + (t)*32)
#define FXG(t) (4096 + (t)*32)
#define FUC    6144
#define FTOT   8192

// ---------- K-1: emb f32 -> bf16 (one row per block) ----------
__global__ void k_cvt_emb(const float* __restrict__ emb, unsigned short* __restrict__ emb16){
  size_t i = (size_t)blockIdx.x*256 + threadIdx.x;
  emb16[i] = f2bf(emb[i]);
}

// ---------- PRE: embed + weight cvt + flags/passthrough ----------
__global__ void k_pre(const int* __restrict__ seqs, const unsigned short* __restrict__ emb16,
                      unsigned short* __restrict__ v16,
                      float* __restrict__ decv, float* __restrict__ genv,
                      unsigned short* __restrict__ barv16,
                      const float* __restrict__ W_ih, const float* __restrict__ Whh,
                      const float* __restrict__ Whk, const float* __restrict__ W1,
                      const float* __restrict__ C1W, const float* __restrict__ C2W,
                      const float* __restrict__ CoW,
                      unsigned short* __restrict__ pool, unsigned char* __restrict__ whh8,
                      const float* __restrict__ sts, const int* __restrict__ label,
                      float* __restrict__ out, unsigned* __restrict__ flags){
  int bx = blockIdx.x, tid = threadIdx.x;
  if (bx < 8192){                       // embed: v = sum_s relu(emb[idx])
    int bt = bx, d = tid;
    const int* sp = seqs + (size_t)bt*Sx;
    float acc = 0.f;
    #pragma unroll 4
    for (int s=0;s<Sx;s++) acc += fmaxf(bf2f(emb16[(size_t)sp[s]*Dx + d]), 0.f);
    size_t o = (size_t)bt*Dx + d;
    v16[o] = f2bf(acc);
    if ((bt & 63) == 0){ decv[o] = acc; genv[o] = acc; barv16[o] = f2bf(acc); }
    return;
  }
  if (bx < 14724){                      // weight conversions
    int i = (bx-8192)*256 + tid;
    if (i < P_TOT){
      float v;
      if      (i < PW_HH) v = W_ih[i - PW_IH];
      else if (i < PW_HK) v = Whh [i - PW_HH];
      else if (i < PW_1 ) v = Whk [i - PW_HK];
      else if (i < PC_1 ) v = W1  [i - PW_1 ];
      else if (i < PC_2 ) v = C1W [i - PC_1 ];
      else if (i < PC_O ) v = C2W [i - PC_2 ];
      else                v = CoW [i - PC_O ];
      pool[i] = f2bf(v);
    } else if (i < P_TOT + 262144){
      whh8[i - P_TOT] = f2e4m3(16.f*Whh[i - P_TOT]);
    }
    return;
  }
  // misc block: flags init + passthrough outputs
  for (int i=tid;i<FTOT;i+=256) flags[i] = (i==FBV(0)) ? 1u : 0u;
  for (int i=tid;i<Bx*Vx;i+=256) out[OFF_STS + i] = sts[i];
  if (tid < Bx) out[OFF_LBL + tid] = (float)label[tid];
}

// ---------- generic MFMA GEMM (xg1 + classifier layers) ----------
template<int MODE_A, int MODE_C, int RELU>
__global__ void k_gemm(const unsigned short* __restrict__ A, const unsigned short* __restrict__ Bw,
                       const float* __restrict__ bias1, const float* __restrict__ bias2,
                       unsigned short* __restrict__ C, int K, int Ntot, float scale){
  int tid = threadIdx.x, w = tid>>6, l = tid&63, lm = l&15, q = l>>4;
  int m0 = blockIdx.x*64;
  int n0 = blockIdx.y*256 + w*64;
  f32x4 acc[4][4];
  #pragma unroll
  for (int nt=0;nt<4;nt++){
    int n = n0 + nt*16 + lm;
    float bz = bias1 ? bias1[n] : 0.f;
    if (bias2) bz += bias2[n];
    #pragma unroll
    for (int mt=0;mt<4;mt++) acc[mt][nt] = (f32x4){bz,bz,bz,bz};
  }
  const s16x8* Arow[4];
  #pragma unroll
  for (int mt=0;mt<4;mt++){
    int m = m0 + mt*16 + lm;
    size_t off = (MODE_A==0) ? (size_t)m*K : ((size_t)(m&127)*Vx + (m>>7))*(size_t)K;
    Arow[mt] = (const s16x8*)(A + off);
  }
  int kkn = K/32;
  for (int kk=0; kk<kkn; kk++){
    s16x8 bfr[4];
    #pragma unroll
    for (int nt=0;nt<4;nt++){
      int n = n0 + nt*16 + lm;
      bfr[nt] = *(const s16x8*)(Bw + (size_t)n*K + kk*32 + q*8);
    }
    #pragma unroll
    for (int mt=0;mt<4;mt++){
      s16x8 afr = Arow[mt][kk*4 + q];
      #pragma unroll
      for (int nt=0;nt<4;nt++)
        acc[mt][nt] = mfma_bf16(afr, bfr[nt], acc[mt][nt]);
    }
  }
  #pragma unroll
  for (int mt=0;mt<4;mt++){
    int mbase = m0 + mt*16 + q*4;
    #pragma unroll
    for (int nt=0;nt<4;nt++){
      int n = n0 + nt*16 + lm;
      if (MODE_C==0){
        #pragma unroll
        for (int r=0;r<4;r++){
          float val = scale*acc[mt][nt][r];
          if (RELU) val = fmaxf(val, 0.f);
          C[(size_t)(mbase+r)*Ntot + n] = f2bf(val);
        }
      } else {
        int tt = mbase>>7, bb = mbase&127;
        int gg = bb>>4;
        s16x4 sv;
        #pragma unroll
        for (int r=0;r<4;r++) sv[r] = (short)f2bf(scale*acc[mt][nt][r]);
        *(s16x4*)(C + (((size_t)tt*8 + gg)*1024 + n)*16 + (bb&15)) = sv;
      }
    }
  }
}

// ---------- scan body (shared by scan1/scan2) ----------
template<int IS1>
DEV void scan_body(unsigned char* hl, const unsigned char* __restrict__ W8,
                   const unsigned short* __restrict__ xg, unsigned short* __restrict__ hist,
                   int g, unsigned* __restrict__ ctr1, unsigned* __restrict__ xgf){
  int tid = threadIdx.x;
  int w = tid>>6, l = tid&63, lm = l&15, q = l>>4;
  int j = w*16 + lm;
  for (int i=tid;i<2*16*HPB;i+=1024) hl[i] = 0;
  long Bf[4][8];
  #pragma unroll
  for (int qq=0;qq<4;qq++){
    int n = qq*256 + j;
    #pragma unroll
    for (int kk=0;kk<8;kk++)
      Bf[qq][kk] = *(const long*)(W8 + (size_t)n*256 + kk*32 + q*8);
  }
  float cst[4] = {0.f,0.f,0.f,0.f};
  const unsigned short* xgb = xg + (size_t)g*16384 + q*4;
  s16x4 xc[4], xn[4];
  if (!IS1) block_wait_ge(&xgf[FXG(0)], 1);
  #pragma unroll
  for (int qq=0;qq<4;qq++) xc[qq] = *(const s16x4*)(xgb + (qq*256+j)*16);
  __syncthreads();
  const float K1 = 1.4426950408889634f/256.f;
  const unsigned char* hrd = hl + lm*HPB + q*8;
  #pragma unroll 1
  for (int t=0;t<Vx;t++){
    if (t < Vx-1){
      if (!IS1) block_wait_ge(&xgf[FXG(t+1)], 1);
      #pragma unroll
      for (int qq=0;qq<4;qq++)
        xn[qq] = *(const s16x4*)(xgb + (size_t)(t+1)*131072 + (qq*256+j)*16);
    }
    const unsigned char* hb = hrd + (t&1)*(16*HPB);
    f32x4 a0, a1, a2, a3;
    #pragma unroll
    for (int r=0;r<4;r++){
      a0[r] = bf2f((unsigned short)xc[0][r]);
      a1[r] = bf2f((unsigned short)xc[1][r]);
      a2[r] = bf2f((unsigned short)xc[2][r]);
      a3[r] = bf2f((unsigned short)xc[3][r]);
    }
    #pragma unroll
    for (int kk=0;kk<8;kk++){
      long af = *(const long*)(hb + kk*32);
      a0 = mfma_fp8(af, Bf[0][kk], a0);
      a1 = mfma_fp8(af, Bf[1][kk], a1);
      a2 = mfma_fp8(af, Bf[2][kk], a2);
      a3 = mfma_fp8(af, Bf[3][kk], a3);
    }
    unsigned char* hn = hl + ((t+1)&1)*(16*HPB) + j;
    float hv16[4];
    #pragma unroll
    for (int r=0;r<4;r++){
      float iv = frcp_(1.f + fexp2_(-K1*a0[r]));
      float fv = frcp_(1.f + fexp2_(-K1*a1[r]));
      float eg = fexp2_(2.f*K1*a2[r]);
      float gv = (eg-1.f)*frcp_(eg+1.f);
      float ov = frcp_(1.f + fexp2_(-K1*a3[r]));
      float cv = fv*cst[r] + iv*gv;
      cst[r] = cv;
      float ec = fexp2_(2.8853900817779268f*fminf(cv,30.f));
      float hv = ov*(ec-1.f)*frcp_(ec+1.f);
      hv16[r] = 16.f*hv;
      if (IS1)
        hist[((size_t)t*Bx + g*16 + q*4 + r)*Hx + j] = f2bf(hv);
      else if (t==Vx-1)
        hist[((size_t)(g*16 + q*4 + r))*Hx + j] = f2bf(hv);
    }
#if __has_builtin(__builtin_amdgcn_cvt_pk_fp8_f32)
    int p01 = __builtin_amdgcn_cvt_pk_fp8_f32(hv16[0], hv16[1], 0, false);
    int p23 = __builtin_amdgcn_cvt_pk_fp8_f32(hv16[2], hv16[3], 0, false);
    hn[(q*4+0)*HPB] = (unsigned char)p01;
    hn[(q*4+1)*HPB] = (unsigned char)(p01>>8);
    hn[(q*4+2)*HPB] = (unsigned char)p23;
    hn[(q*4+3)*HPB] = (unsigned char)(p23>>8);
#else
    #pragma unroll
    for (int r=0;r<4;r++) hn[(q*4+r)*HPB] = f2e4m3(hv16[r]);
#endif
    #pragma unroll
    for (int qq=0;qq<4;qq++) xc[qq] = xn[qq];
    if (IS1){
      __syncthreads();                           // drains hist stores (vmcnt 0)
      if (tid == 0) aadd_rel(&ctr1[FCT(t)], 1);  // publish h[t]
    } else {
      lds_barrier();
    }
  }
}

// ---------- per-t chain worker: wh -> attn -> barv -> xg2 ----------
DEV void worker_body(unsigned short* whs, int t,
    const unsigned short* __restrict__ hist1, const unsigned short* __restrict__ v16,
    const float* __restrict__ u, const unsigned short* __restrict__ pool,
    const float* __restrict__ bhk, const float* __restrict__ W2, const float* __restrict__ b2,
    const float* __restrict__ b_ih, const float* __restrict__ b_hh,
    float* __restrict__ decv, float* __restrict__ genv,
    unsigned short* __restrict__ barv16, unsigned short* __restrict__ xg2,
    unsigned* flags){
  int tid = threadIdx.x, w = tid>>6, l = tid&63, lm = l&15, q = l>>4;
  if (t < 63){
    block_wait_ge(&flags[FCT(t)], 8);           // scan1 step t done (all 8 blocks)
    // ---- wh tile: 128x256, wave w -> rows (w&7)*16, cols (w>>3)*128 ----
    int r0 = (w&7)*16, n0 = (w>>3)*128;
    const s16x8* Arow = (const s16x8*)(hist1 + ((size_t)t*Bx + r0 + lm)*Hx);
    f32x4 acc[8];
    #pragma unroll
    for (int nt=0;nt<8;nt++){
      float bz = bhk[n0 + nt*16 + lm];
      acc[nt] = (f32x4){bz,bz,bz,bz};
    }
    #pragma unroll
    for (int kk=0;kk<8;kk++){
      s16x8 afr = Arow[kk*4 + q];
      #pragma unroll
      for (int nt=0;nt<8;nt++){
        int n = n0 + nt*16 + lm;
        s16x8 bfr = *(const s16x8*)(pool + PW_HK + (size_t)n*256 + kk*32 + q*8);
        acc[nt] = mfma_bf16(afr, bfr, acc[nt]);
      }
    }
    #pragma unroll
    for (int nt=0;nt<8;nt++){
      int n = n0 + nt*16 + lm, mb = r0 + q*4;
      #pragma unroll
      for (int r=0;r<4;r++) whs[(size_t)(mb+r)*WHP + n] = f2bf(acc[nt][r]);
    }
    if (tid == 0) spin_ge(&flags[FUC], 8);      // u ready
    __syncthreads();                            // + orders whs stores
    // ---- attn on waves 0..7 (16 rows each) ----
    if (w < 8){
      int m0l = w*16;
      f32x4 a2[4];
      #pragma unroll
      for (int nt=0;nt<4;nt++){
        int n = nt*16 + lm;
        #pragma unroll
        for (int r=0;r<4;r++) a2[nt][r] = u[(size_t)(m0l + q*4 + r)*64 + n];
      }
      #pragma unroll
      for (int kk=0;kk<8;kk++){
        s16x8 afr = *(const s16x8*)(whs + (size_t)(m0l+lm)*WHP + kk*32 + q*8);
        #pragma unroll
        for (int nt=0;nt<4;nt++){
          int n = nt*16 + lm;
          s16x8 bfr = *(const s16x8*)(pool + PW_1 + (size_t)n*512 + 256 + kk*32 + q*8);
          a2[nt] = mfma_bf16(afr, bfr, a2[nt]);
        }
      }
      float p0a[4] = {0,0,0,0}, p1a[4] = {0,0,0,0};
      #pragma unroll
      for (int nt=0;nt<4;nt++){
        int n = nt*16 + lm;
        float w2a = W2[n], w2b = W2[64+n];
        #pragma unroll
        for (int r=0;r<4;r++){
          float z = tanh_(a2[nt][r]);
          p0a[r] += z*w2a; p1a[r] += z*w2b;
        }
      }
      #pragma unroll
      for (int s=1;s<16;s<<=1){
        #pragma unroll
        for (int r=0;r<4;r++){ p0a[r] += __shfl_xor(p0a[r], s, 16); p1a[r] += __shfl_xor(p1a[r], s, 16); }
      }
      float bb0 = b2[0], bb1 = b2[1];
      int d0 = lm*16;
      #pragma unroll
      for (int r=0;r<4;r++){
        int b = m0l + q*4 + r;
        float g0 = p0a[r]+bb0, g1 = p1a[r]+bb1;
        float al0 = frcp_(1.f + fexp2_(1.4426950408889634f*(g1-g0)));
        float al1 = 1.f - al0;
        const unsigned short* ek  = v16 + (size_t)b*Vx*Dx + d0;
        const unsigned short* whp = whs + (size_t)b*WHP + d0;
        size_t ob = ((size_t)b*Vx + (t+1))*Dx + d0;
        #pragma unroll
        for (int c=0;c<2;c++){
          s16x8 e8 = *(const s16x8*)(ek + c*8);
          s16x8 w8 = *(const s16x8*)(whp + c*8);
          s16x8 o16;
          #pragma unroll
          for (int jj=0;jj<8;jj++){
            float o = al0*bf2f((unsigned short)e8[jj]) + al1*bf2f((unsigned short)w8[jj]);
            decv[ob + c*8 + jj] = o;
            genv[ob + c*8 + jj] = o;
            o16[jj] = (short)f2bf(o);
          }
          *(s16x8*)(barv16 + ob + c*8) = o16;
        }
      }
    }
    __syncthreads();                            // drains barv stores
    if (tid == 0) astore_rel(&flags[FBV(t+1)], 1);
  }
  // ---- phase B: xg2 tile t (128 x 1024, K=256) ----
  block_wait_ge(&flags[FBV(t)], 1);
  int mh = (w&1)*64, nb = (w>>1)*128;
  const s16x8* Arow2[4];
  #pragma unroll
  for (int mt=0;mt<4;mt++)
    Arow2[mt] = (const s16x8*)(barv16 + ((size_t)(mh + mt*16 + lm)*Vx + t)*Dx);
  #pragma unroll 1
  for (int sc=0; sc<4; sc++){
    int n0 = nb + sc*32;
    f32x4 acc[4][2];
    #pragma unroll
    for (int nt=0;nt<2;nt++){
      int n = n0 + nt*16 + lm;
      float bz = b_ih[n] + b_hh[n];
      #pragma unroll
      for (int mt=0;mt<4;mt++) acc[mt][nt] = (f32x4){bz,bz,bz,bz};
    }
    #pragma unroll
    for (int kk=0;kk<8;kk++){
      s16x8 bfr[2];
      #pragma unroll
      for (int nt=0;nt<2;nt++){
        int n = n0 + nt*16 + lm;
        bfr[nt] = *(const s16x8*)(pool + PW_IH + (size_t)n*256 + kk*32 + q*8);
      }
      #pragma unroll
      for (int mt=0;mt<4;mt++){
        s16x8 afr = Arow2[mt][kk*4 + q];
        acc[mt][0] = mfma_bf16(afr, bfr[0], acc[mt][0]);
        acc[mt][1] = mfma_bf16(afr, bfr[1], acc[mt][1]);
      }
    }
    #pragma unroll
    for (int mt=0;mt<4;mt++){
      int m = mh + mt*16 + q*4;
      int gg = m>>4;
      #pragma unroll
      for (int nt=0;nt<2;nt++){
        int n = n0 + nt*16 + lm;
        s16x4 sv;
        #pragma unroll
        for (int r=0;r<4;r++) sv[r] = (short)f2bf(256.f*acc[mt][nt][r]);
        *(s16x4*)(xg2 + (((size_t)t*8 + gg)*1024 + n)*16 + (m&15)) = sv;
      }
    }
  }
  __syncthreads();                              // drains xg2 stores
  if (tid == 0) astore_rel(&flags[FXG(t)], 1);
}

// ---------- MEGA: scan1 || workers || scan2 || u ----------
__global__ __launch_bounds__(1024) void k_mega(
    const unsigned char* __restrict__ W8,
    const unsigned short* __restrict__ xg1, unsigned short* __restrict__ xg2,
    unsigned short* __restrict__ hist1, unsigned short* __restrict__ h2,
    const unsigned short* __restrict__ v16, float* __restrict__ u,
    const unsigned short* __restrict__ pool,
    const float* __restrict__ bhk, const float* __restrict__ W2, const float* __restrict__ b2,
    const float* __restrict__ b1, const float* __restrict__ b_ih, const float* __restrict__ b_hh,
    float* __restrict__ decv, float* __restrict__ genv, unsigned short* __restrict__ barv16,
    unsigned* __restrict__ flags){
  __shared__ __align__(16) unsigned char smem[69632];
  int blk = blockIdx.x;
  if (blk < 8){
    scan_body<1>(smem, W8, xg1, hist1, blk, flags, flags);
  } else if (blk < 16){
    scan_body<0>(smem, W8, xg2, h2, blk-8, flags, flags);
  } else if (blk < 80){
    worker_body((unsigned short*)smem, blk-16, hist1, v16, u, pool, bhk, W2, b2,
                b_ih, b_hh, decv, genv, barv16, xg2, flags);
  } else {
    // u GEMV: 8 blocks x 1024 threads = 8192 = 128 b x 64 n
    int t2 = (blk-80)*1024 + threadIdx.x;
    int b = t2>>6, n = t2&63;
    const s16x8* vr = (const s16x8*)(v16 + (size_t)b*Vx*Dx);
    const s16x8* wr = (const s16x8*)(pool + PW_1 + (size_t)n*512);
    float a = b1[n];
    for (int kk=0;kk<32;kk++){
      s16x8 x = vr[kk], ww = wr[kk];
      #pragma unroll
      for (int jj=0;jj<8;jj++) a += bf2f((unsigned short)x[jj])*bf2f((unsigned short)ww[jj]);
    }
    u[t2] = a;
    __syncthreads();                            // drains u stores
    if (threadIdx.x == 0) aadd_rel(&flags[FUC], 1);
  }
}

// ---------- final logits: out = y2 @ CoW^T + Cob ----------
__global__ void k_out(const unsigned short* __restrict__ y2, const unsigned short* __restrict__ CoW16,
                      const float* __restrict__ Cob, float* __restrict__ out){
  int tid = blockIdx.x*256 + threadIdx.x;
  int m = tid>>1, n = tid&1;
  const s16x8* yr = (const s16x8*)(y2 + (size_t)m*512);
  const s16x8* wr = (const s16x8*)(CoW16 + (size_t)n*512);
  float a = Cob[n];
  for (int kk=0;kk<64;kk++){
    s16x8 yv = yr[kk], ww = wr[kk];
    #pragma unroll
    for (int jj=0;jj<8;jj++) a += bf2f((unsigned short)yv[jj])*bf2f((unsigned short)ww[jj]);
  }
  int base = (m < 128) ? (OFF_OG + m*2) : (OFF_FAKE + (m-128)*2);
  out[base + n] = a;
}

// ---------- launch ----------
extern "C" void kernel_launch(void* const* d_in, const int* in_sizes, int n_in,
                              void* d_out, int out_size, void* d_ws, size_t ws_size,
                              hipStream_t stream) {
  const int*   seqs  = (const int*)d_in[0];
  const float* sts   = (const float*)d_in[3];
  const int*   label = (const int*)d_in[5];
  const float* emb   = (const float*)d_in[6];
  const float* W_ih  = (const float*)d_in[7];
  const float* W_hh  = (const float*)d_in[8];
  const float* b_ih  = (const float*)d_in[9];
  const float* b_hh  = (const float*)d_in[10];
  const float* Whk   = (const float*)d_in[11];
  const float* bhk   = (const float*)d_in[12];
  const float* W1    = (const float*)d_in[13];
  const float* b1    = (const float*)d_in[14];
  const float* W2    = (const float*)d_in[15];
  const float* b2    = (const float*)d_in[16];
  const float* C1b   = (const float*)d_in[18];
  const float* C2b   = (const float*)d_in[20];
  const float* Cob   = (const float*)d_in[22];
  float* out = (float*)d_out;

  char* ws = (char*)d_ws;
  unsigned short* v16    = (unsigned short*)(ws + 0);            //  4 MiB [b][t][d] bf16
  unsigned short* xg1    = (unsigned short*)(ws + (4<<20));      // 16 MiB [t][g][n][16] (x256)
  unsigned short* hist1  = (unsigned short*)(ws + (20<<20));     //  4 MiB [t][b][j] + 64K h2
  unsigned short* barv16 = (unsigned short*)(ws + (25<<20));     //  4 MiB [b][t][d] bf16
  unsigned short* xg2    = (unsigned short*)(ws + (29<<20));     // 16 MiB (workers write)
  unsigned short* emb16  = xg2;                                  // overlay: dead before mega
  float*          u      = (float*)(ws + (45<<20));              // 32 KiB
  unsigned char*  whh8   = (unsigned char*)(ws + (45<<20) + (64<<10));   // 256 KiB
  unsigned*       flags  = (unsigned*)(ws + (45<<20) + (384<<10));       // 32 KiB padded flags
  unsigned short* pool   = (unsigned short*)(ws + (46<<20));     // 2.82 MiB
  unsigned short* y1     = xg1;                                  // overlay (xg1 dead post-mega)
  unsigned short* y2     = xg1 + 262144;

  unsigned short* h2 = hist1 + (size_t)Vx*Bx*Hx;
  unsigned short* X  = hist1 + (size_t)(Vx-1)*Bx*Hx;   // [256][256]: h1[63] ; h2

  float* decv = out + OFF_DECV;
  float* genv = out + OFF_GENV;

  k_cvt_emb<<<dim3(NVOC), dim3(256), 0, stream>>>(emb, emb16);
  k_pre<<<dim3(14725), dim3(256), 0, stream>>>(seqs, emb16, v16, decv, genv, barv16,
      W_ih, W_hh, Whk, W1, (const float*)d_in[17], (const float*)d_in[19],
      (const float*)d_in[21], pool, whh8, sts, label, out, flags);
  k_gemm<1,1,0><<<dim3(128,4), dim3(256), 0, stream>>>(v16, pool+PW_IH, b_ih, b_hh, xg1, 256, 1024, 256.f);
  k_mega<<<dim3(88), dim3(1024), 0, stream>>>(whh8, xg1, xg2, hist1, h2, v16, u, pool,
      bhk, W2, b2, b1, b_ih, b_hh, decv, genv, barv16, flags);
  k_gemm<0,0,1><<<dim3(4,4), dim3(256), 0, stream>>>(X, pool+PC_1, C1b, nullptr, y1, 256, 1024, 1.f);
  k_gemm<0,0,1><<<dim3(4,2), dim3(256), 0, stream>>>(y1, pool+PC_2, C2b, nullptr, y2, 1024, 512, 1.f);
  k_out<<<dim3(2), dim3(256), 0, stream>>>(y2, pool+PC_O, Cob, out);
}

// Round 9
// 537.439 us; speedup vs baseline: 1.2772x; 1.0280x over previous
//
#include <hip/hip_runtime.h>

#define DEV __device__ __forceinline__

typedef float f32x4 __attribute__((ext_vector_type(4)));
typedef short s16x8 __attribute__((ext_vector_type(8)));
typedef short s16x4 __attribute__((ext_vector_type(4)));

// ---------- scalar helpers ----------
DEV unsigned short f2bf(float f){
  unsigned int u = __float_as_uint(f);
  u += 0x7fffu + ((u>>16)&1u);
  return (unsigned short)(u>>16);
}
DEV float bf2f(unsigned short h){ return __uint_as_float(((unsigned int)h)<<16); }

#if __has_builtin(__builtin_amdgcn_rcpf)
DEV float frcp_(float x){ return __builtin_amdgcn_rcpf(x); }
#else
DEV float frcp_(float x){ return 1.f/x; }
#endif
#if __has_builtin(__builtin_amdgcn_exp2f)
DEV float fexp2_(float x){ return __builtin_amdgcn_exp2f(x); }
#else
DEV float fexp2_(float x){ return exp2f(x); }
#endif

DEV float tanh_(float x){
  x = fminf(x, 30.f);
  float e = fexp2_(2.8853900817779268f*x);
  return (e-1.f)*frcp_(e+1.f);
}

// branchless f32 -> OCP e4m3fn (fallback when no HW cvt)
DEV unsigned char f2e4m3(float x){
  unsigned int u = __float_as_uint(x);
  unsigned int s = (u>>24)&0x80u;
  unsigned int mag = u & 0x7fffffffu;
  if (mag > 0x43E00000u) mag = 0x43E00000u;
  mag += 0x000FFFFFu + ((mag>>20)&1u);
  int e = (int)(mag>>23) - 120;
  unsigned int m = (mag>>20)&7u;
  unsigned int r = (e<=0) ? 0u : (((unsigned)e<<3)|m);
  return (unsigned char)(s|r);
}

DEV f32x4 mfma_bf16(s16x8 a, s16x8 b, f32x4 c){
  return __builtin_amdgcn_mfma_f32_16x16x32_bf16(a,b,c,0,0,0);
}
DEV f32x4 mfma_fp8(long a, long b, f32x4 c){
  return __builtin_amdgcn_mfma_f32_16x16x32_fp8_fp8(a,b,c,0,0,0);
}

// LDS-only barrier (no vmcnt drain)
DEV void lds_barrier(){
  asm volatile("s_waitcnt lgkmcnt(0)\n\ts_barrier" ::: "memory");
}

// ---------- sync primitives ----------
// RELAXED agent polls: coherent read, NO per-poll cache invalidate.
// One explicit acquire fence (L2 inv) only where plain loads follow.
DEV unsigned aload_rlx(unsigned* p){
  return __hip_atomic_load(p, __ATOMIC_RELAXED, __HIP_MEMORY_SCOPE_AGENT);
}
DEV void astore_rel(unsigned* p, unsigned v){
  __hip_atomic_store(p, v, __ATOMIC_RELEASE, __HIP_MEMORY_SCOPE_AGENT);
}
DEV void aadd_rel(unsigned* p, unsigned v){
  __hip_atomic_fetch_add(p, v, __ATOMIC_RELEASE, __HIP_MEMORY_SCOPE_AGENT);
}
DEV void acq_fence(){ __builtin_amdgcn_fence(__ATOMIC_ACQUIRE, "agent"); }
DEV void spin_rlx(unsigned* p, unsigned tgt){
  while (aload_rlx(p) < tgt) __builtin_amdgcn_s_sleep(8);
  asm volatile("" ::: "memory");
}
// block wait; FENCE=1 -> one acquire fence (for subsequent plain loads)
template<int FENCE>
DEV void block_wait_ge(unsigned* p, unsigned tgt){
  if (threadIdx.x == 0){
    spin_rlx(p, tgt);
    if (FENCE) acq_fence();
  }
  __syncthreads();
}
// relaxed agent-scope 64-bit data load (reads coherence point; no fence needed)
DEV s16x4 aload64(const unsigned short* p){
  unsigned long long v = __hip_atomic_load((unsigned long long*)(void*)p,
      __ATOMIC_RELAXED, __HIP_MEMORY_SCOPE_AGENT);
  union { unsigned long long u; s16x4 s; } c; c.u = v; return c.s;
}

// ---------- problem constants ----------
#define Bx 128
#define Vx 64
#define Sx 40
#define Dx 256
#define Hx 256
#define NVOC 20001

// d_out element offsets (f32)
#define OFF_OG   0
#define OFF_FAKE 256
#define OFF_DECV 512
#define OFF_GENV 2097664
#define OFF_STS  4194816
#define OFF_LBL  4203008

// bf16 weight-pool element offsets
#define PW_IH  0
#define PW_HH  262144
#define PW_HK  524288
#define PW_1   589824
#define PC_1   622592
#define PC_2   884736
#define PC_O   1409024
#define P_TOT  1410048

#define HPB 264      // scan LDS row pitch (bytes)
#define WHP 272      // worker wh LDS pitch (shorts)

// flag slots (ints): one per 128-B line
#define FCT(t) ((t)*32)
#define FBV(t) (2048 + (t)*32)
#define FXG(t) (4096 + (t)*32)
#define FUC    6144
#define FTOT   8192

// ---------- K-1: emb f32 -> bf16 ----------
__global__ void k_cvt_emb(const float* __restrict__ emb, unsigned short* __restrict__ emb16){
  size_t i = (size_t)blockIdx.x*256 + threadIdx.x;
  emb16[i] = f2bf(emb[i]);
}

// ---------- PRE: embed + weight cvt + flags/passthrough ----------
__global__ void k_pre(const int* __restrict__ seqs, const unsigned short* __restrict__ emb16,
                      unsigned short* __restrict__ v16,
                      float* __restrict__ decv, float* __restrict__ genv,
                      unsigned short* __restrict__ barv16,
                      const float* __restrict__ W_ih, const float* __restrict__ Whh,
                      const float* __restrict__ Whk, const float* __restrict__ W1,
                      const float* __restrict__ C1W, const float* __restrict__ C2W,
                      const float* __restrict__ CoW,
                      unsigned short* __restrict__ pool, unsigned char* __restrict__ whh8,
                      const float* __restrict__ sts, const int* __restrict__ label,
                      float* __restrict__ out, unsigned* __restrict__ flags){
  int bx = blockIdx.x, tid = threadIdx.x;
  if (bx < 8192){                       // embed: v = sum_s relu(emb[idx])
    int bt = bx, d = tid;
    const int* sp = seqs + (size_t)bt*Sx;
    float acc = 0.f;
    #pragma unroll 8
    for (int s=0;s<Sx;s++) acc += fmaxf(bf2f(emb16[(size_t)sp[s]*Dx + d]), 0.f);
    size_t o = (size_t)bt*Dx + d;
    v16[o] = f2bf(acc);
    if ((bt & 63) == 0){ decv[o] = acc; genv[o] = acc; barv16[o] = f2bf(acc); }
    return;
  }
  if (bx < 14724){                      // weight conversions
    int i = (bx-8192)*256 + tid;
    if (i < P_TOT){
      float v;
      if      (i < PW_HH) v = W_ih[i - PW_IH];
      else if (i < PW_HK) v = Whh [i - PW_HH];
      else if (i < PW_1 ) v = Whk [i - PW_HK];
      else if (i < PC_1 ) v = W1  [i - PW_1 ];
      else if (i < PC_2 ) v = C1W [i - PC_1 ];
      else if (i < PC_O ) v = C2W [i - PC_2 ];
      else                v = CoW [i - PC_O ];
      pool[i] = f2bf(v);
    } else if (i < P_TOT + 262144){
      whh8[i - P_TOT] = f2e4m3(16.f*Whh[i - P_TOT]);
    }
    return;
  }
  // misc block: flags init + passthrough outputs
  for (int i=tid;i<FTOT;i+=256) flags[i] = (i==FBV(0)) ? 1u : 0u;
  for (int i=tid;i<Bx*Vx;i+=256) out[OFF_STS + i] = sts[i];
  if (tid < Bx) out[OFF_LBL + tid] = (float)label[tid];
}

// ---------- generic MFMA GEMM (xg1 + classifier layers) ----------
template<int MODE_A, int MODE_C, int RELU>
__global__ void k_gemm(const unsigned short* __restrict__ A, const unsigned short* __restrict__ Bw,
                       const float* __restrict__ bias1, const float* __restrict__ bias2,
                       unsigned short* __restrict__ C, int K, int Ntot, float scale){
  int tid = threadIdx.x, w = tid>>6, l = tid&63, lm = l&15, q = l>>4;
  int m0 = blockIdx.x*64;
  int n0 = blockIdx.y*256 + w*64;
  f32x4 acc[4][4];
  #pragma unroll
  for (int nt=0;nt<4;nt++){
    int n = n0 + nt*16 + lm;
    float bz = bias1 ? bias1[n] : 0.f;
    if (bias2) bz += bias2[n];
    #pragma unroll
    for (int mt=0;mt<4;mt++) acc[mt][nt] = (f32x4){bz,bz,bz,bz};
  }
  const s16x8* Arow[4];
  #pragma unroll
  for (int mt=0;mt<4;mt++){
    int m = m0 + mt*16 + lm;
    size_t off = (MODE_A==0) ? (size_t)m*K : ((size_t)(m&127)*Vx + (m>>7))*(size_t)K;
    Arow[mt] = (const s16x8*)(A + off);
  }
  int kkn = K/32;
  for (int kk=0; kk<kkn; kk++){
    s16x8 bfr[4];
    #pragma unroll
    for (int nt=0;nt<4;nt++){
      int n = n0 + nt*16 + lm;
      bfr[nt] = *(const s16x8*)(Bw + (size_t)n*K + kk*32 + q*8);
    }
    #pragma unroll
    for (int mt=0;mt<4;mt++){
      s16x8 afr = Arow[mt][kk*4 + q];
      #pragma unroll
      for (int nt=0;nt<4;nt++)
        acc[mt][nt] = mfma_bf16(afr, bfr[nt], acc[mt][nt]);
    }
  }
  #pragma unroll
  for (int mt=0;mt<4;mt++){
    int mbase = m0 + mt*16 + q*4;
    #pragma unroll
    for (int nt=0;nt<4;nt++){
      int n = n0 + nt*16 + lm;
      if (MODE_C==0){
        #pragma unroll
        for (int r=0;r<4;r++){
          float val = scale*acc[mt][nt][r];
          if (RELU) val = fmaxf(val, 0.f);
          C[(size_t)(mbase+r)*Ntot + n] = f2bf(val);
        }
      } else {
        int tt = mbase>>7, bb = mbase&127;
        int gg = bb>>4;
        s16x4 sv;
        #pragma unroll
        for (int r=0;r<4;r++) sv[r] = (short)f2bf(scale*acc[mt][nt][r]);
        *(s16x4*)(C + (((size_t)tt*8 + gg)*1024 + n)*16 + (bb&15)) = sv;
      }
    }
  }
}

// ---------- scan body (shared by scan1/scan2) ----------
template<int IS1>
DEV void scan_body(unsigned char* hl, const unsigned char* __restrict__ W8,
                   const unsigned short* __restrict__ xg, unsigned short* __restrict__ hist,
                   int g, unsigned* __restrict__ flags){
  int tid = threadIdx.x;
  int w = tid>>6, l = tid&63, lm = l&15, q = l>>4;
  int j = w*16 + lm;
  for (int i=tid;i<2*16*HPB;i+=1024) hl[i] = 0;
  long Bf[4][8];
  #pragma unroll
  for (int qq=0;qq<4;qq++){
    int n = qq*256 + j;
    #pragma unroll
    for (int kk=0;kk<8;kk++)
      Bf[qq][kk] = *(const long*)(W8 + (size_t)n*256 + kk*32 + q*8);
  }
  float cst[4] = {0.f,0.f,0.f,0.f};
  const unsigned short* xgb = xg + (size_t)g*16384 + q*4;
  s16x4 xc[4], xn[4];
  if (!IS1) block_wait_ge<0>(&flags[FXG(0)], 1);
  #pragma unroll
  for (int qq=0;qq<4;qq++){
    const unsigned short* p = xgb + (qq*256+j)*16;
    xc[qq] = IS1 ? *(const s16x4*)p : aload64(p);
  }
  __syncthreads();
  const float K1 = 1.4426950408889634f/256.f;
  const unsigned char* hrd = hl + lm*HPB + q*8;
  #pragma unroll 1
  for (int t=0;t<Vx;t++){
    if (t < Vx-1){
      if (!IS1) block_wait_ge<0>(&flags[FXG(t+1)], 1);
      #pragma unroll
      for (int qq=0;qq<4;qq++){
        const unsigned short* p = xgb + (size_t)(t+1)*131072 + (qq*256+j)*16;
        xn[qq] = IS1 ? *(const s16x4*)p : aload64(p);
      }
    }
    const unsigned char* hb = hrd + (t&1)*(16*HPB);
    f32x4 a0, a1, a2, a3;
    #pragma unroll
    for (int r=0;r<4;r++){
      a0[r] = bf2f((unsigned short)xc[0][r]);
      a1[r] = bf2f((unsigned short)xc[1][r]);
      a2[r] = bf2f((unsigned short)xc[2][r]);
      a3[r] = bf2f((unsigned short)xc[3][r]);
    }
    #pragma unroll
    for (int kk=0;kk<8;kk++){
      long af = *(const long*)(hb + kk*32);
      a0 = mfma_fp8(af, Bf[0][kk], a0);
      a1 = mfma_fp8(af, Bf[1][kk], a1);
      a2 = mfma_fp8(af, Bf[2][kk], a2);
      a3 = mfma_fp8(af, Bf[3][kk], a3);
    }
    unsigned char* hn = hl + ((t+1)&1)*(16*HPB) + j;
    float hv16[4];
    #pragma unroll
    for (int r=0;r<4;r++){
      float iv = frcp_(1.f + fexp2_(-K1*a0[r]));
      float fv = frcp_(1.f + fexp2_(-K1*a1[r]));
      float eg = fexp2_(2.f*K1*a2[r]);
      float gv = (eg-1.f)*frcp_(eg+1.f);
      float ov = frcp_(1.f + fexp2_(-K1*a3[r]));
      float cv = fv*cst[r] + iv*gv;
      cst[r] = cv;
      float ec = fexp2_(2.8853900817779268f*fminf(cv,30.f));
      float hv = ov*(ec-1.f)*frcp_(ec+1.f);
      hv16[r] = 16.f*hv;
      if (IS1)
        hist[((size_t)t*Bx + g*16 + q*4 + r)*Hx + j] = f2bf(hv);
      else if (t==Vx-1)
        hist[((size_t)(g*16 + q*4 + r))*Hx + j] = f2bf(hv);
    }
#if __has_builtin(__builtin_amdgcn_cvt_pk_fp8_f32)
    int p01 = __builtin_amdgcn_cvt_pk_fp8_f32(hv16[0], hv16[1], 0, false);
    int p23 = __builtin_amdgcn_cvt_pk_fp8_f32(hv16[2], hv16[3], 0, false);
    hn[(q*4+0)*HPB] = (unsigned char)p01;
    hn[(q*4+1)*HPB] = (unsigned char)(p01>>8);
    hn[(q*4+2)*HPB] = (unsigned char)p23;
    hn[(q*4+3)*HPB] = (unsigned char)(p23>>8);
#else
    #pragma unroll
    for (int r=0;r<4;r++) hn[(q*4+r)*HPB] = f2e4m3(hv16[r]);
#endif
    #pragma unroll
    for (int qq=0;qq<4;qq++) xc[qq] = xn[qq];
    if (IS1){
      __syncthreads();                           // drains hist stores (vmcnt 0)
      if (tid == 0) aadd_rel(&flags[FCT(t)], 1); // publish h[t] (wbl2 once/step)
    } else {
      lds_barrier();
    }
  }
}

// ---------- per-t chain worker: wh -> attn -> barv -> xg2 ----------
DEV void worker_body(unsigned short* whs, int t,
    const unsigned short* __restrict__ hist1, const unsigned short* __restrict__ v16,
    const float* __restrict__ u, const unsigned short* __restrict__ pool,
    const float* __restrict__ bhk, const float* __restrict__ W2, const float* __restrict__ b2,
    const float* __restrict__ b_ih, const float* __restrict__ b_hh,
    float* __restrict__ decv, float* __restrict__ genv,
    unsigned short* __restrict__ barv16, unsigned short* __restrict__ xg2,
    unsigned* flags){
  int tid = threadIdx.x, w = tid>>6, l = tid&63, lm = l&15, q = l>>4;
  if (t < 63){
    block_wait_ge<1>(&flags[FCT(t)], 8);        // scan1 step t done; fence for hist1 reads
    // ---- wh tile: 128x256, wave w -> rows (w&7)*16, cols (w>>3)*128 ----
    int r0 = (w&7)*16, n0 = (w>>3)*128;
    const s16x8* Arow = (const s16x8*)(hist1 + ((size_t)t*Bx + r0 + lm)*Hx);
    f32x4 acc[8];
    #pragma unroll
    for (int nt=0;nt<8;nt++){
      float bz = bhk[n0 + nt*16 + lm];
      acc[nt] = (f32x4){bz,bz,bz,bz};
    }
    #pragma unroll
    for (int kk=0;kk<8;kk++){
      s16x8 afr = Arow[kk*4 + q];
      #pragma unroll
      for (int nt=0;nt<8;nt++){
        int n = n0 + nt*16 + lm;
        s16x8 bfr = *(const s16x8*)(pool + PW_HK + (size_t)n*256 + kk*32 + q*8);
        acc[nt] = mfma_bf16(afr, bfr, acc[nt]);
      }
    }
    #pragma unroll
    for (int nt=0;nt<8;nt++){
      int n = n0 + nt*16 + lm, mb = r0 + q*4;
      #pragma unroll
      for (int r=0;r<4;r++) whs[(size_t)(mb+r)*WHP + n] = f2bf(acc[nt][r]);
    }
    if (tid == 0){ spin_rlx(&flags[FUC], 8); acq_fence(); }   // u ready
    __syncthreads();                            // + orders whs stores
    // ---- attn on waves 0..7 (16 rows each) ----
    if (w < 8){
      int m0l = w*16;
      f32x4 a2[4];
      #pragma unroll
      for (int nt=0;nt<4;nt++){
        int n = nt*16 + lm;
        #pragma unroll
        for (int r=0;r<4;r++) a2[nt][r] = u[(size_t)(m0l + q*4 + r)*64 + n];
      }
      #pragma unroll
      for (int kk=0;kk<8;kk++){
        s16x8 afr = *(const s16x8*)(whs + (size_t)(m0l+lm)*WHP + kk*32 + q*8);
        #pragma unroll
        for (int nt=0;nt<4;nt++){
          int n = nt*16 + lm;
          s16x8 bfr = *(const s16x8*)(pool + PW_1 + (size_t)n*512 + 256 + kk*32 + q*8);
          a2[nt] = mfma_bf16(afr, bfr, a2[nt]);
        }
      }
      float p0a[4] = {0,0,0,0}, p1a[4] = {0,0,0,0};
      #pragma unroll
      for (int nt=0;nt<4;nt++){
        int n = nt*16 + lm;
        float w2a = W2[n], w2b = W2[64+n];
        #pragma unroll
        for (int r=0;r<4;r++){
          float z = tanh_(a2[nt][r]);
          p0a[r] += z*w2a; p1a[r] += z*w2b;
        }
      }
      #pragma unroll
      for (int s=1;s<16;s<<=1){
        #pragma unroll
        for (int r=0;r<4;r++){ p0a[r] += __shfl_xor(p0a[r], s, 16); p1a[r] += __shfl_xor(p1a[r], s, 16); }
      }
      float bb0 = b2[0], bb1 = b2[1];
      int d0 = lm*16;
      #pragma unroll
      for (int r=0;r<4;r++){
        int b = m0l + q*4 + r;
        float g0 = p0a[r]+bb0, g1 = p1a[r]+bb1;
        float al0 = frcp_(1.f + fexp2_(1.4426950408889634f*(g1-g0)));
        float al1 = 1.f - al0;
        const unsigned short* ek  = v16 + (size_t)b*Vx*Dx + d0;
        const unsigned short* whp = whs + (size_t)b*WHP + d0;
        size_t ob = ((size_t)b*Vx + (t+1))*Dx + d0;
        #pragma unroll
        for (int c=0;c<2;c++){
          s16x8 e8 = *(const s16x8*)(ek + c*8);
          s16x8 w8 = *(const s16x8*)(whp + c*8);
          s16x8 o16;
          #pragma unroll
          for (int jj=0;jj<8;jj++){
            float o = al0*bf2f((unsigned short)e8[jj]) + al1*bf2f((unsigned short)w8[jj]);
            decv[ob + c*8 + jj] = o;
            genv[ob + c*8 + jj] = o;
            o16[jj] = (short)f2bf(o);
          }
          *(s16x8*)(barv16 + ob + c*8) = o16;
        }
      }
    }
    __syncthreads();                            // drains barv stores
    if (tid == 0) astore_rel(&flags[FBV(t+1)], 1);
  }
  // ---- phase B: xg2 tile t (128 x 1024, K=256) ----
  block_wait_ge<1>(&flags[FBV(t)], 1);          // fence for barv16 reads
  int mh = (w&1)*64, nb = (w>>1)*128;
  const s16x8* Arow2[4];
  #pragma unroll
  for (int mt=0;mt<4;mt++)
    Arow2[mt] = (const s16x8*)(barv16 + ((size_t)(mh + mt*16 + lm)*Vx + t)*Dx);
  #pragma unroll 1
  for (int sc=0; sc<4; sc++){
    int n0 = nb + sc*32;
    f32x4 acc[4][2];
    #pragma unroll
    for (int nt=0;nt<2;nt++){
      int n = n0 + nt*16 + lm;
      float bz = b_ih[n] + b_hh[n];
      #pragma unroll
      for (int mt=0;mt<4;mt++) acc[mt][nt] = (f32x4){bz,bz,bz,bz};
    }
    #pragma unroll
    for (int kk=0;kk<8;kk++){
      s16x8 bfr[2];
      #pragma unroll
      for (int nt=0;nt<2;nt++){
        int n = n0 + nt*16 + lm;
        bfr[nt] = *(const s16x8*)(pool + PW_IH + (size_t)n*256 + kk*32 + q*8);
      }
      #pragma unroll
      for (int mt=0;mt<4;mt++){
        s16x8 afr = Arow2[mt][kk*4 + q];
        acc[mt][0] = mfma_bf16(afr, bfr[0], acc[mt][0]);
        acc[mt][1] = mfma_bf16(afr, bfr[1], acc[mt][1]);
      }
    }
    #pragma unroll
    for (int mt=0;mt<4;mt++){
      int m = mh + mt*16 + q*4;
      int gg = m>>4;
      #pragma unroll
      for (int nt=0;nt<2;nt++){
        int n = n0 + nt*16 + lm;
        s16x4 sv;
        #pragma unroll
        for (int r=0;r<4;r++) sv[r] = (short)f2bf(256.f*acc[mt][nt][r]);
        *(s16x4*)(xg2 + (((size_t)t*8 + gg)*1024 + n)*16 + (m&15)) = sv;
      }
    }
  }
  __syncthreads();                              // drains xg2 stores
  if (tid == 0) astore_rel(&flags[FXG(t)], 1);
}

// ---------- MEGA: scan1 || workers || scan2 || u ----------
__global__ __launch_bounds__(1024) void k_mega(
    const unsigned char* __restrict__ W8,
    const unsigned short* __restrict__ xg1, unsigned short* __restrict__ xg2,
    unsigned short* __restrict__ hist1, unsigned short* __restrict__ h2,
    const unsigned short* __restrict__ v16, float* __restrict__ u,
    const unsigned short* __restrict__ pool,
    const float* __restrict__ bhk, const float* __restrict__ W2, const float* __restrict__ b2,
    const float* __restrict__ b1, const float* __restrict__ b_ih, const float* __restrict__ b_hh,
    float* __restrict__ decv, float* __restrict__ genv, unsigned short* __restrict__ barv16,
    unsigned* __restrict__ flags){
  __shared__ __align__(16) unsigned char smem[69632];
  int blk = blockIdx.x;
  if (blk < 8){
    scan_body<1>(smem, W8, xg1, hist1, blk, flags);
  } else if (blk < 16){
    scan_body<0>(smem, W8, xg2, h2, blk-8, flags);
  } else if (blk < 80){
    worker_body((unsigned short*)smem, blk-16, hist1, v16, u, pool, bhk, W2, b2,
                b_ih, b_hh, decv, genv, barv16, xg2, flags);
  } else {
    // u GEMV: 8 blocks x 1024 threads = 8192 = 128 b x 64 n
    int t2 = (blk-80)*1024 + threadIdx.x;
    int b = t2>>6, n = t2&63;
    const s16x8* vr = (const s16x8*)(v16 + (size_t)b*Vx*Dx);
    const s16x8* wr = (const s16x8*)(pool + PW_1 + (size_t)n*512);
    float a = b1[n];
    for (int kk=0;kk<32;kk++){
      s16x8 x = vr[kk], ww = wr[kk];
      #pragma unroll
      for (int jj=0;jj<8;jj++) a += bf2f((unsigned short)x[jj])*bf2f((unsigned short)ww[jj]);
    }
    u[t2] = a;
    __syncthreads();                            // drains u stores
    if (threadIdx.x == 0) aadd_rel(&flags[FUC], 1);
  }
}

// ---------- final logits: out = y2 @ CoW^T + Cob ----------
__global__ void k_out(const unsigned short* __restrict__ y2, const unsigned short* __restrict__ CoW16,
                      const float* __restrict__ Cob, float* __restrict__ out){
  int tid = blockIdx.x*256 + threadIdx.x;
  int m = tid>>1, n = tid&1;
  const s16x8* yr = (const s16x8*)(y2 + (size_t)m*512);
  const s16x8* wr = (const s16x8*)(CoW16 + (size_t)n*512);
  float a = Cob[n];
  for (int kk=0;kk<64;kk++){
    s16x8 yv = yr[kk], ww = wr[kk];
    #pragma unroll
    for (int jj=0;jj<8;jj++) a += bf2f((unsigned short)yv[jj])*bf2f((unsigned short)ww[jj]);
  }
  int base = (m < 128) ? (OFF_OG + m*2) : (OFF_FAKE + (m-128)*2);
  out[base + n] = a;
}

// ---------- launch ----------
extern "C" void kernel_launch(void* const* d_in, const int* in_sizes, int n_in,
                              void* d_out, int out_size, void* d_ws, size_t ws_size,
                              hipStream_t stream) {
  const int*   seqs  = (const int*)d_in[0];
  const float* sts   = (const float*)d_in[3];
  const int*   label = (const int*)d_in[5];
  const float* emb   = (const float*)d_in[6];
  const float* W_ih  = (const float*)d_in[7];
  const float* W_hh  = (const float*)d_in[8];
  const float* b_ih  = (const float*)d_in[9];
  const float* b_hh  = (const float*)d_in[10];
  const float* Whk   = (const float*)d_in[11];
  const float* bhk   = (const float*)d_in[12];
  const float* W1    = (const float*)d_in[13];
  const float* b1    = (const float*)d_in[14];
  const float* W2    = (const float*)d_in[15];
  const float* b2    = (const float*)d_in[16];
  const float* C1b   = (const float*)d_in[18];
  const float* C2b   = (const float*)d_in[20];
  const float* Cob   = (const float*)d_in[22];
  float* out = (float*)d_out;

  char* ws = (char*)d_ws;
  unsigned short* v16    = (unsigned short*)(ws + 0);            //  4 MiB [b][t][d] bf16
  unsigned short* xg1    = (unsigned short*)(ws + (4<<20));      // 16 MiB [t][g][n][16] (x256)
  unsigned short* hist1  = (unsigned short*)(ws + (20<<20));     //  4 MiB [t][b][j] + 64K h2
  unsigned short* barv16 = (unsigned short*)(ws + (25<<20));     //  4 MiB [b][t][d] bf16
  unsigned short* xg2    = (unsigned short*)(ws + (29<<20));     // 16 MiB (workers write)
  unsigned short* emb16  = xg2;                                  // overlay: dead before mega
  float*          u      = (float*)(ws + (45<<20));              // 32 KiB
  unsigned char*  whh8   = (unsigned char*)(ws + (45<<20) + (64<<10));   // 256 KiB
  unsigned*       flags  = (unsigned*)(ws + (45<<20) + (384<<10));       // 32 KiB padded flags
  unsigned short* pool   = (unsigned short*)(ws + (46<<20));     // 2.82 MiB
  unsigned short* y1     = xg1;                                  // overlay (xg1 dead post-mega)
  unsigned short* y2     = xg1 + 262144;

  unsigned short* h2 = hist1 + (size_t)Vx*Bx*Hx;
  unsigned short* X  = hist1 + (size_t)(Vx-1)*Bx*Hx;   // [256][256]: h1[63] ; h2

  float* decv = out + OFF_DECV;
  float* genv = out + OFF_GENV;

  k_cvt_emb<<<dim3(NVOC), dim3(256), 0, stream>>>(emb, emb16);
  k_pre<<<dim3(14725), dim3(256), 0, stream>>>(seqs, emb16, v16, decv, genv, barv16,
      W_ih, W_hh, Whk, W1, (const float*)d_in[17], (const float*)d_in[19],
      (const float*)d_in[21], pool, whh8, sts, label, out, flags);
  k_gemm<1,1,0><<<dim3(128,4), dim3(256), 0, stream>>>(v16, pool+PW_IH, b_ih, b_hh, xg1, 256, 1024, 256.f);
  k_mega<<<dim3(88), dim3(1024), 0, stream>>>(whh8, xg1, xg2, hist1, h2, v16, u, pool,
      bhk, W2, b2, b1, b_ih, b_hh, decv, genv, barv16, flags);
  k_gemm<0,0,1><<<dim3(4,4), dim3(256), 0, stream>>>(X, pool+PC_1, C1b, nullptr, y1, 256, 1024, 1.f);
  k_gemm<0,0,1><<<dim3(4,2), dim3(256), 0, stream>>>(y1, pool+PC_2, C2b, nullptr, y2, 1024, 512, 1.f);
  k_out<<<dim3(2), dim3(256), 0, stream>>>(y2, pool+PC_O, Cob, out);
}